// Round 1
// baseline (899.803 us; speedup 1.0000x reference)
//
#include <hip/hip_runtime.h>

// Problem constants: N=8, C=128, O=128, H=W=80, 3x3 kernel, pad 1, stride 1.
#define NB 8
#define CH 128
#define OC 128
#define HH 80
#define WW 80
#define HWSZ 6400      // 80*80
#define KTAPS 9
#define KDIM 1152      // C*9

// ---------------------------------------------------------------------------
// k0: transpose main conv weights: wT[kk][o] = w[o][kk]  (kk = c*9+k)
// ---------------------------------------------------------------------------
__global__ __launch_bounds__(256) void transpose_w(const float* __restrict__ w,
                                                   float* __restrict__ wT) {
    int idx = blockIdx.x * 256 + threadIdx.x;   // 576 blocks -> 147456
    int o  = idx & 127;
    int kk = idx >> 7;
    wT[kk * 128 + o] = w[o * KDIM + kk];
}

// ---------------------------------------------------------------------------
// k1: offset conv (3x3, C=128 -> 18), direct.  grid = 8*18*25 = 3600 blocks.
//   blockIdx.x = ((n*18 + oc)*25 + hb); block covers 256 consecutive pixels.
// ---------------------------------------------------------------------------
__global__ __launch_bounds__(256) void offset_conv(const float* __restrict__ x,
                                                   const float* __restrict__ w_off,
                                                   const float* __restrict__ b_off,
                                                   float* __restrict__ offs) {
    int bx = blockIdx.x;
    int n  = bx / 450;          // 18*25
    int r  = bx % 450;
    int oc = r / 25;            // block-uniform -> scalar weight loads
    int hb = r % 25;
    int pix = hb * 256 + threadIdx.x;   // 0..6399
    int h = pix / 80;
    int w = pix % 80;

    float acc = b_off[oc];
    const float* wbase = w_off + oc * KDIM;
    const float* xn = x + (size_t)n * CH * HWSZ;

    #pragma unroll
    for (int ky = 0; ky < 3; ++ky) {
        int row = h + ky - 1;
        if ((unsigned)row >= (unsigned)HH) continue;
        #pragma unroll
        for (int kx = 0; kx < 3; ++kx) {
            int col = w + kx - 1;
            if ((unsigned)col >= (unsigned)WW) continue;
            const float* xp = xn + row * 80 + col;
            const float* wp = wbase + ky * 3 + kx;
            #pragma unroll 8
            for (int c = 0; c < 128; ++c) {
                acc = fmaf(xp[c * HWSZ], wp[c * 9], acc);
            }
        }
    }
    offs[((size_t)n * 18 + oc) * HWSZ + h * 80 + w] = acc;
}

// ---------------------------------------------------------------------------
// k2: deformable conv as implicit GEMM.
//   Tile: 2 rows x 16 cols = 32 pixels per block.  grid = (5, 40, 8).
//   K = 1152 processed in 4 chunks of 288 (32 channels x 9 taps).
//   Phase A: 288 (tap,pixel) pairs -> bilinear gather -> v_lds.
//   Phase B: 256 threads, each 4 o x 4 p register tile, fp32 FMA.
// ---------------------------------------------------------------------------
__global__ __launch_bounds__(256) void deform_gemm(const float* __restrict__ x,
                                                   const float* __restrict__ offs,
                                                   const float* __restrict__ wT,
                                                   const float* __restrict__ b,
                                                   float* __restrict__ out) {
    __shared__ float v_lds[288 * 32];   // 36864 B

    const int t  = threadIdx.x;
    const int w0 = blockIdx.x * 16;
    const int h0 = blockIdx.y * 2;
    const int n  = blockIdx.z;

    const float* xn = x + (size_t)n * CH * HWSZ;

    // ---- per-pair bilinear setup (pair = k*32 + p, p = ph*16 + pw) ----
    int   idx00[2], idx01[2], idx10[2], idx11[2];
    float g00[2], g01[2], g10[2], g11[2];
    const int npairs = (t < 32) ? 2 : 1;
    for (int s = 0; s < npairs; ++s) {
        int pair = t + s * 256;          // < 288
        int k = pair >> 5;
        int p = pair & 31;
        int ph = p >> 4, pw = p & 15;
        int hh = h0 + ph, ww = w0 + pw;
        int obase = ((n * 18 + 2 * k) * HWSZ) + hh * 80 + ww;
        float dy = offs[obase];
        float dx = offs[obase + HWSZ];
        float py = (float)(hh + k / 3 - 1) + dy;
        float px = (float)(ww + k % 3 - 1) + dx;
        float y0f = floorf(py), x0f = floorf(px);
        int y0 = (int)y0f, x0 = (int)x0f;
        float fy = py - y0f, fx = px - x0f;
        int y0c = min(max(y0, 0), 79),     y1c = min(max(y0 + 1, 0), 79);
        int x0c = min(max(x0, 0), 79),     x1c = min(max(x0 + 1, 0), 79);
        float my0 = (y0 >= 0 && y0 < 80) ? 1.f : 0.f;
        float my1 = (y0 + 1 >= 0 && y0 + 1 < 80) ? 1.f : 0.f;
        float mx0 = (x0 >= 0 && x0 < 80) ? 1.f : 0.f;
        float mx1 = (x0 + 1 >= 0 && x0 + 1 < 80) ? 1.f : 0.f;
        idx00[s] = y0c * 80 + x0c;  g00[s] = (1.f - fy) * (1.f - fx) * my0 * mx0;
        idx01[s] = y0c * 80 + x1c;  g01[s] = (1.f - fy) * fx * my0 * mx1;
        idx10[s] = y1c * 80 + x0c;  g10[s] = fy * (1.f - fx) * my1 * mx0;
        idx11[s] = y1c * 80 + x1c;  g11[s] = fy * fx * my1 * mx1;
    }

    const int o0 = (t & 31) * 4;         // output-channel sub-tile
    const int p0 = (t >> 5) * 4;         // pixel sub-tile

    float acc[4][4];
    #pragma unroll
    for (int i = 0; i < 4; ++i)
        #pragma unroll
        for (int j = 0; j < 4; ++j) acc[i][j] = 0.f;

    for (int c0 = 0; c0 < 128; c0 += 32) {
        __syncthreads();   // previous GEMM reads done before overwriting v_lds
        // ---- Phase A: bilinear gather into LDS ----
        for (int s = 0; s < npairs; ++s) {
            int pair = t + s * 256;
            const float* xc = xn + (size_t)c0 * HWSZ;
            float* vd = &v_lds[pair];
            int i00 = idx00[s], i01 = idx01[s], i10 = idx10[s], i11 = idx11[s];
            float a00 = g00[s], a01 = g01[s], a10 = g10[s], a11 = g11[s];
            #pragma unroll 4
            for (int cl = 0; cl < 32; ++cl) {
                const float* xp = xc + cl * HWSZ;
                float vv = a00 * xp[i00] + a01 * xp[i01]
                         + a10 * xp[i10] + a11 * xp[i11];
                vd[cl * 288] = vv;       // addr = cl*288 + k*32 + p (lane-consecutive)
            }
        }
        __syncthreads();
        // ---- Phase B: 288-deep GEMM step ----
        const float* wrow = wT + (size_t)(c0 * 9) * 128 + o0;
        const float* vrow = &v_lds[p0];
        #pragma unroll 4
        for (int kk = 0; kk < 288; ++kk) {
            float4 vv4 = *(const float4*)(vrow + kk * 32);
            float4 ww4 = *(const float4*)(wrow + kk * 128);
            float vj[4] = {vv4.x, vv4.y, vv4.z, vv4.w};
            float wi[4] = {ww4.x, ww4.y, ww4.z, ww4.w};
            #pragma unroll
            for (int i = 0; i < 4; ++i)
                #pragma unroll
                for (int j = 0; j < 4; ++j)
                    acc[i][j] = fmaf(wi[i], vj[j], acc[i][j]);
        }
    }

    // ---- epilogue: bias + float4 stores ----
    const int row = h0 + (p0 >> 4);
    const int col = w0 + (p0 & 15);
    #pragma unroll
    for (int i = 0; i < 4; ++i) {
        int o = o0 + i;
        float bias = b[o];
        float4 st = make_float4(acc[i][0] + bias, acc[i][1] + bias,
                                acc[i][2] + bias, acc[i][3] + bias);
        *(float4*)&out[((size_t)(n * OC + o)) * HWSZ + row * 80 + col] = st;
    }
}

// ---------------------------------------------------------------------------
extern "C" void kernel_launch(void* const* d_in, const int* in_sizes, int n_in,
                              void* d_out, int out_size, void* d_ws, size_t ws_size,
                              hipStream_t stream) {
    const float* x     = (const float*)d_in[0];   // (8,128,80,80)
    const float* w_off = (const float*)d_in[1];   // (18,128,3,3)
    const float* b_off = (const float*)d_in[2];   // (18,)
    const float* wmain = (const float*)d_in[3];   // (128,128,3,3)
    const float* bias  = (const float*)d_in[4];   // (128,)
    float* out = (float*)d_out;                   // (8,128,80,80)

    float* offs = (float*)d_ws;                   // 8*18*6400 floats = 14.75 MB
    float* wT   = offs + (size_t)NB * 18 * HWSZ;  // 1152*128 floats = 0.59 MB

    transpose_w<<<576, 256, 0, stream>>>(wmain, wT);
    offset_conv<<<3600, 256, 0, stream>>>(x, w_off, b_off, offs);
    deform_gemm<<<dim3(5, 40, 8), 256, 0, stream>>>(x, offs, wT, bias, out);
}

// Round 2
// 761.492 us; speedup vs baseline: 1.1816x; 1.1816x over previous
//
#include <hip/hip_runtime.h>

#define HWSZ 6400      // 80*80
#define RH 14          // staged window rows
#define RW 28          // staged window cols
#define RPX 392        // RH*RW used pixels per channel
#define XSTR 398       // padded channel stride in xs (elems) -> 199 dwords (odd)
#define VSTR 296       // padded row stride in v_lds (elems), 16B aligned

typedef short bf16x8 __attribute__((ext_vector_type(8)));
typedef float f32x4 __attribute__((ext_vector_type(4)));

__device__ inline ushort f2bf(float f) {
    uint u = __float_as_uint(f);
    u += 0x7fffu + ((u >> 16) & 1u);     // RNE
    return (ushort)(u >> 16);
}
__device__ inline float bf2f(ushort u) {
    return __uint_as_float((uint)u << 16);
}
__device__ inline uint pk2(float a, float b) {
    return (uint)f2bf(a) | ((uint)f2bf(b) << 16);
}

// ---------------------------------------------------------------------------
// prep: wR[o][k*128+c] = bf16(w[o][c][k])  (tap-major K for MFMA)
//       wo2[(c*9+k)*18+oc] = w_off[oc][c][k]
// ---------------------------------------------------------------------------
__global__ __launch_bounds__(256) void prep_weights(const float* __restrict__ w,
                                                    const float* __restrict__ w_off,
                                                    ushort* __restrict__ wR,
                                                    float* __restrict__ wo2) {
    int idx = blockIdx.x * 256 + threadIdx.x;
    if (idx < 147456) {
        int o = idx / 1152, r = idx - o * 1152;
        int k = r >> 7, c = r & 127;
        wR[idx] = f2bf(w[(o * 128 + c) * 9 + k]);
    } else if (idx < 147456 + 20736) {
        int i = idx - 147456;
        int ck = i / 18, oc = i - ck * 18;
        wo2[i] = w_off[oc * 1152 + ck];
    }
}

// ---------------------------------------------------------------------------
// offset conv: thread-per-pixel, 18 accumulators, x read once.
// grid = 51200/256 = 200 blocks.
// ---------------------------------------------------------------------------
__global__ __launch_bounds__(256) void offset_conv(const float* __restrict__ x,
                                                   const float* __restrict__ wo2,
                                                   const float* __restrict__ b_off,
                                                   float* __restrict__ offs) {
    int pixg = blockIdx.x * 256 + threadIdx.x;
    int n = pixg / HWSZ, p = pixg - n * HWSZ;
    int h = p / 80, w = p - h * 80;
    float acc[18];
    #pragma unroll
    for (int oc = 0; oc < 18; ++oc) acc[oc] = b_off[oc];
    const float* xn = x + (size_t)n * 128 * HWSZ;
    #pragma unroll
    for (int k = 0; k < 9; ++k) {
        int row = h + k / 3 - 1, col = w + k % 3 - 1;
        bool ok = (unsigned)row < 80u && (unsigned)col < 80u;
        const float* xp = xn + row * 80 + col;
        const float* wp = wo2 + k * 18;
        #pragma unroll 2
        for (int c = 0; c < 128; ++c) {
            float xv = ok ? xp[c * HWSZ] : 0.f;
            #pragma unroll
            for (int oc = 0; oc < 18; ++oc)
                acc[oc] = fmaf(xv, wp[c * 162 + oc], acc[oc]);
        }
    }
    #pragma unroll
    for (int oc = 0; oc < 18; ++oc)
        offs[((size_t)n * 18 + oc) * HWSZ + p] = acc[oc];
}

// ---------------------------------------------------------------------------
// deformable conv: 2x16 pixel tile, K=1152 in 4 chunks of (9 taps x 32 ch).
//   Phase 0: bilinear setup per (tap,pixel) -> LDS -> regs (9 units/thread).
//   Per chunk: stage x window (bf16, zero halo) -> LDS gather -> v_lds
//              -> bf16 MFMA (4 waves x 32o x 32p, 16x16x32).
// grid = (5, 40, 8).
// ---------------------------------------------------------------------------
__global__ __launch_bounds__(256) void deform_gemm(const float* __restrict__ x,
                                                   const float* __restrict__ offs,
                                                   const ushort* __restrict__ wR,
                                                   const float* __restrict__ b,
                                                   float* __restrict__ out) {
    __shared__ ushort xs[32 * XSTR];     // 25472 B
    __shared__ ushort v_lds[32 * VSTR];  // 18944 B (first 5760 B overlaid w/ setup)

    const int t = threadIdx.x;
    const int w0 = blockIdx.x * 16;
    const int h0 = blockIdx.y * 2;
    const int n  = blockIdx.z;
    const int rh0 = h0 - 6, rw0 = w0 - 6;
    const float* xn = x + (size_t)n * 128 * HWSZ;

    // ---- Phase 0: bilinear setup records into LDS ----
    float* setup = (float*)v_lds;        // 288 records x 5 floats
    #pragma unroll
    for (int s = 0; s < 2; ++s) {
        int pair = t + s * 256;
        if (pair < 288) {
            int k = pair >> 5, p = pair & 31;
            int hh = h0 + (p >> 4), ww = w0 + (p & 15);
            size_t ob = ((size_t)(n * 18 + 2 * k)) * HWSZ + hh * 80 + ww;
            float dy = offs[ob], dx = offs[ob + HWSZ];
            float py  = (float)(hh + k / 3 - 1) + dy;
            float px_ = (float)(ww + k % 3 - 1) + dx;
            float y0f = floorf(py), x0f = floorf(px_);
            int y0 = (int)y0f, x0 = (int)x0f;
            float fy = py - y0f, fx = px_ - x0f;
            bool win = (y0 >= rh0) && (y0 <= rh0 + RH - 2) &&
                       (x0 >= rw0) && (x0 <= rw0 + RW - 2);
            int pb = win ? (y0 - rh0) * RW + (x0 - rw0) : -1;
            setup[pair * 5 + 0] = __int_as_float(pb);
            setup[pair * 5 + 1] = (1.f - fy) * (1.f - fx);
            setup[pair * 5 + 2] = (1.f - fy) * fx;
            setup[pair * 5 + 3] = fy * (1.f - fx);
            setup[pair * 5 + 4] = fy * fx;
        }
    }
    __syncthreads();

    // ---- setups to registers: unit u = t + j*256, pair=u>>3, ch-group=u&7 ----
    int spb[9]; float sg[9][4];
    #pragma unroll
    for (int j = 0; j < 9; ++j) {
        int base = ((t + j * 256) >> 3) * 5;
        spb[j]   = __float_as_int(setup[base]);
        sg[j][0] = setup[base + 1];
        sg[j][1] = setup[base + 2];
        sg[j][2] = setup[base + 3];
        sg[j][3] = setup[base + 4];
    }

    const int lane = t & 63;
    const int o_w  = (t >> 6) * 32;      // wave's 32 output channels
    f32x4 acc[2][2];
    #pragma unroll
    for (int oi = 0; oi < 2; ++oi)
        #pragma unroll
        for (int pj = 0; pj < 2; ++pj) {
            f32x4 z = {0.f, 0.f, 0.f, 0.f};
            acc[oi][pj] = z;
        }

    for (int c0 = 0; c0 < 128; c0 += 32) {
        __syncthreads();   // setups consumed / prior chunk done with xs & v_lds
        // ---- stage x window as bf16, zero halo (6368 dword writes) ----
        for (int i = 0; i < 25; ++i) {
            int e2 = t + i * 256;
            if (e2 < 6368) {
                int ch = e2 / 199, px2 = e2 - ch * 199;
                int px = px2 * 2;
                uint vpk = 0u;
                if (px < RPX) {
                    int row = px / RW, col = px - row * RW;
                    int gy = rh0 + row, gx = rw0 + col;
                    const float* xc = xn + (size_t)(c0 + ch) * HWSZ + gy * 80 + gx;
                    bool okr = (unsigned)gy < 80u;
                    float f0 = (okr && (unsigned)gx < 80u) ? xc[0] : 0.f;
                    float f1 = (okr && (unsigned)(gx + 1) < 80u) ? xc[1] : 0.f;
                    vpk = pk2(f0, f1);
                }
                ((uint*)xs)[e2] = vpk;
            }
        }
        __syncthreads();
        // ---- Phase A: bilinear gather -> v_lds (9 units/thread x 4 ch) ----
        #pragma unroll
        for (int j = 0; j < 9; ++j) {
            int u = t + j * 256;
            int pair = u >> 3, cg = u & 7;
            int k = pair >> 5, p = pair & 31;
            float val[4];
            if (spb[j] >= 0) {
                #pragma unroll
                for (int cc = 0; cc < 4; ++cc) {
                    const ushort* xb = xs + (cg * 4 + cc) * XSTR + spb[j];
                    val[cc] = sg[j][0] * bf2f(xb[0])  + sg[j][1] * bf2f(xb[1])
                            + sg[j][2] * bf2f(xb[RW]) + sg[j][3] * bf2f(xb[RW + 1]);
                }
            } else {
                // rare fallback: |offset| beyond window -> global gather
                int hh = h0 + (p >> 4), ww = w0 + (p & 15);
                size_t ob = ((size_t)(n * 18 + 2 * k)) * HWSZ + hh * 80 + ww;
                float dy = offs[ob], dx = offs[ob + HWSZ];
                float py  = (float)(hh + k / 3 - 1) + dy;
                float px_ = (float)(ww + k % 3 - 1) + dx;
                float y0f = floorf(py), x0f = floorf(px_);
                int y0 = (int)y0f, x0 = (int)x0f;
                float fy = py - y0f, fx = px_ - x0f;
                float my0 = (unsigned)y0 < 80u ? 1.f : 0.f;
                float my1 = (unsigned)(y0 + 1) < 80u ? 1.f : 0.f;
                float mx0 = (unsigned)x0 < 80u ? 1.f : 0.f;
                float mx1 = (unsigned)(x0 + 1) < 80u ? 1.f : 0.f;
                int y0c = min(max(y0, 0), 79), y1c = min(max(y0 + 1, 0), 79);
                int x0c = min(max(x0, 0), 79), x1c = min(max(x0 + 1, 0), 79);
                int i00 = y0c * 80 + x0c, i01 = y0c * 80 + x1c;
                int i10 = y1c * 80 + x0c, i11 = y1c * 80 + x1c;
                float G00 = (1.f - fy) * (1.f - fx) * my0 * mx0;
                float G01 = (1.f - fy) * fx * my0 * mx1;
                float G10 = fy * (1.f - fx) * my1 * mx0;
                float G11 = fy * fx * my1 * mx1;
                #pragma unroll
                for (int cc = 0; cc < 4; ++cc) {
                    const float* xc = xn + (size_t)(c0 + cg * 4 + cc) * HWSZ;
                    val[cc] = G00 * xc[i00] + G01 * xc[i01]
                            + G10 * xc[i10] + G11 * xc[i11];
                }
            }
            uint2* dst = (uint2*)(v_lds + p * VSTR + k * 32 + cg * 4);
            *dst = make_uint2(pk2(val[0], val[1]), pk2(val[2], val[3]));
        }
        __syncthreads();
        // ---- Phase B: 9 MFMA K-steps (tap-major), 4 mfma each ----
        #pragma unroll
        for (int s = 0; s < 9; ++s) {
            const ushort* wa = wR + (size_t)(o_w + (lane & 15)) * 1152
                             + s * 128 + c0 + 8 * (lane >> 4);
            bf16x8 a0 = *(const bf16x8*)wa;
            bf16x8 a1 = *(const bf16x8*)(wa + 16 * 1152);
            const ushort* vb = v_lds + (lane & 15) * VSTR + s * 32 + 8 * (lane >> 4);
            bf16x8 b0 = *(const bf16x8*)vb;
            bf16x8 b1 = *(const bf16x8*)(vb + 16 * VSTR);
            acc[0][0] = __builtin_amdgcn_mfma_f32_16x16x32_bf16(a0, b0, acc[0][0], 0, 0, 0);
            acc[0][1] = __builtin_amdgcn_mfma_f32_16x16x32_bf16(a0, b1, acc[0][1], 0, 0, 0);
            acc[1][0] = __builtin_amdgcn_mfma_f32_16x16x32_bf16(a1, b0, acc[1][0], 0, 0, 0);
            acc[1][1] = __builtin_amdgcn_mfma_f32_16x16x32_bf16(a1, b1, acc[1][1], 0, 0, 0);
        }
    }

    // ---- epilogue: bias + store (coalesced in 16-lane groups) ----
    #pragma unroll
    for (int oi = 0; oi < 2; ++oi)
        #pragma unroll
        for (int pj = 0; pj < 2; ++pj)
            #pragma unroll
            for (int r = 0; r < 4; ++r) {
                int o = o_w + oi * 16 + (lane >> 4) * 4 + r;
                int col = lane & 15;
                out[((size_t)(n * 128 + o)) * HWSZ + (h0 + pj) * 80 + w0 + col]
                    = acc[oi][pj][r] + b[o];
            }
}

// ---------------------------------------------------------------------------
extern "C" void kernel_launch(void* const* d_in, const int* in_sizes, int n_in,
                              void* d_out, int out_size, void* d_ws, size_t ws_size,
                              hipStream_t stream) {
    const float* x     = (const float*)d_in[0];   // (8,128,80,80)
    const float* w_off = (const float*)d_in[1];   // (18,128,3,3)
    const float* b_off = (const float*)d_in[2];   // (18,)
    const float* wmain = (const float*)d_in[3];   // (128,128,3,3)
    const float* bias  = (const float*)d_in[4];   // (128,)
    float* out = (float*)d_out;                   // (8,128,80,80)

    float*  offs = (float*)d_ws;                        // 921600 f = 3.69 MB
    ushort* wR   = (ushort*)(offs + 921600);            // 147456 bf16 = 288 KB
    float*  wo2  = (float*)((char*)wR + 147456 * 2);    // 20736 f = 81 KB

    prep_weights<<<657, 256, 0, stream>>>(wmain, w_off, wR, wo2);
    offset_conv<<<200, 256, 0, stream>>>(x, wo2, b_off, offs);
    deform_gemm<<<dim3(5, 40, 8), 256, 0, stream>>>(x, offs, wR, bias, out);
}

// Round 5
// 84.794 us; speedup vs baseline: 10.6116x; 8.9805x over previous
//
#include <hip/hip_runtime.h>

#define HWSZ 6400          // 80*80
#define PP   96            // padded plane dim (y,x in [-8,87])
#define PLANE (PP*PP*128)  // elems per padded plane (1,179,648; 2,359,296 B)
#define VSTR 392           // v_lds row stride (elems): 384 + 8 pad

typedef short bf16x8 __attribute__((ext_vector_type(8)));
typedef float f32x4  __attribute__((ext_vector_type(4)));
typedef uint  u32x4  __attribute__((ext_vector_type(4)));

__device__ inline ushort f2bf(float f) {
    uint u = __float_as_uint(f);
    u += 0x7fffu + ((u >> 16) & 1u);     // RNE
    return (ushort)(u >> 16);
}
__device__ inline float bf2f(ushort u) {
    return __uint_as_float((uint)u << 16);
}
__device__ inline uint pk2(float a, float b) {
    return (uint)f2bf(a) | ((uint)f2bf(b) << 16);
}

// ---------------------------------------------------------------------------
// prep: fragment-major bf16 weights.
//   wA   [ot 0..7][S 0..35][lane 0..63][j 0..7]  (main conv, o = ot*16+(lane&15))
//   wAoff[ot 0..1][S 0..35][lane 0..63][j 0..7]  (offset conv, rows >=18 zero)
//   K = S*32 + 8*(lane>>4) + j ; tap k = K>>7 ; c = K&127  (tap-major K)
// ---------------------------------------------------------------------------
__global__ __launch_bounds__(256) void prep_weights(const float* __restrict__ w,
                                                    const float* __restrict__ w_off,
                                                    ushort* __restrict__ wA,
                                                    ushort* __restrict__ wAoff) {
    int idx = blockIdx.x * 256 + threadIdx.x;
    if (idx < 147456) {
        int ot = idx / 18432, rem = idx - ot * 18432;
        int s = rem >> 9, lane = (rem >> 3) & 63, j = rem & 7;
        int o = ot * 16 + (lane & 15);
        int K = s * 32 + 8 * (lane >> 4) + j;
        int k = K >> 7, c = K & 127;
        wA[idx] = f2bf(w[(o * 128 + c) * 9 + k]);
    } else if (idx < 147456 + 36864) {
        int i = idx - 147456;
        int ot = i / 18432, rem = i - ot * 18432;
        int s = rem >> 9, lane = (rem >> 3) & 63, j = rem & 7;
        int o = ot * 16 + (lane & 15);
        int K = s * 32 + 8 * (lane >> 4) + j;
        int k = K >> 7, c = K & 127;
        wAoff[i] = (o < 18) ? f2bf(w_off[(o * 128 + c) * 9 + k]) : (ushort)0;
    }
}

// ---------------------------------------------------------------------------
// transpose x -> padded NHWC bf16 plane g: xTp[g][y+8][x+8][c], x from n_base+g.
// grid (80 h, G), block 256.
// ---------------------------------------------------------------------------
__global__ __launch_bounds__(256) void transpose_x(const float* __restrict__ x,
                                                   ushort* __restrict__ xTp,
                                                   int n_base) {
    __shared__ ushort st[80 * 136];      // [w][c]; 136 -> 16B-aligned rows
    int h = blockIdx.x, g = blockIdx.y;
    int t = threadIdx.x;
    const float* xn = x + ((size_t)(n_base + g) * 128) * HWSZ + h * 80;
    for (int i = 0; i < 40; ++i) {
        int e = t + i * 256;             // e = c*80 + w   (10240 total)
        int c = e / 80;
        int wcol = e - c * 80;
        st[wcol * 136 + c] = f2bf(xn[(size_t)c * HWSZ + wcol]);
    }
    __syncthreads();
    ushort* dst = xTp + (size_t)g * PLANE + ((size_t)(h + 8) * PP + 8) * 128;
    for (int i = 0; i < 5; ++i) {
        int e = t + i * 256;             // e = w*16 + cq   (1280 x 16B units)
        int wcol = e >> 4, cq = e & 15;  // cq unit = 8 ushorts
        u32x4 v = *(const u32x4*)(st + wcol * 136 + cq * 8);
        *(u32x4*)(dst + (size_t)wcol * 128 + cq * 8) = v;
    }
}

// ---------------------------------------------------------------------------
// offset conv as MFMA im2col GEMM.  Tile 4x16 px, 4 waves (one px-row each).
// grid (5, 20, G), block 256.  Plane g -> offs[g].
// ---------------------------------------------------------------------------
__global__ __launch_bounds__(256) void offset_mfma(const ushort* __restrict__ xTp,
                                                   const ushort* __restrict__ wAoff,
                                                   const float* __restrict__ b_off,
                                                   float* __restrict__ offs) {
    __shared__ ushort xs[6 * 18 * 136];  // 29376 B
    int t = threadIdx.x;
    int w0 = blockIdx.x * 16, h0 = blockIdx.y * 4, g = blockIdx.z;
    const ushort* xb = xTp + (size_t)g * PLANE + ((size_t)(h0 + 7) * PP + (w0 + 7)) * 128;
    for (int i = 0; i < 7; ++i) {
        int e = t + i * 256;
        if (e < 1728) {                  // 6 rows x 18 cols x 16 cq
            int r = e / 288, rem = e - r * 288;
            int col = rem >> 4, cq = rem & 15;
            u32x4 v = *(const u32x4*)(xb + ((size_t)r * PP + col) * 128 + cq * 8);
            *(u32x4*)(xs + (r * 18 + col) * 136 + cq * 8) = v;
        }
    }
    __syncthreads();
    int lane = t & 63, wv = t >> 6;
    f32x4 acc0 = {0.f, 0.f, 0.f, 0.f};
    f32x4 acc1 = {0.f, 0.f, 0.f, 0.f};
    #pragma unroll
    for (int k = 0; k < 9; ++k) {
        int ky = k / 3, kx = k - ky * 3;
        #pragma unroll
        for (int q = 0; q < 4; ++q) {
            int s = k * 4 + q;
            bf16x8 a0 = *(const bf16x8*)(wAoff + ((size_t)(0 * 36 + s) * 64 + lane) * 8);
            bf16x8 a1 = *(const bf16x8*)(wAoff + ((size_t)(1 * 36 + s) * 64 + lane) * 8);
            bf16x8 bb = *(const bf16x8*)(xs + ((wv + ky) * 18 + (lane & 15) + kx) * 136
                                          + q * 32 + 8 * (lane >> 4));
            acc0 = __builtin_amdgcn_mfma_f32_16x16x32_bf16(a0, bb, acc0, 0, 0, 0);
            acc1 = __builtin_amdgcn_mfma_f32_16x16x32_bf16(a1, bb, acc1, 0, 0, 0);
        }
    }
    int col = lane & 15, rg = lane >> 4;
    int prow = h0 + wv, pcol = w0 + col;
    #pragma unroll
    for (int r = 0; r < 4; ++r) {
        int oc = rg * 4 + r;
        offs[((size_t)(g * 18 + oc)) * HWSZ + prow * 80 + pcol] = acc0[r] + b_off[oc];
    }
    if (rg == 0) {
        #pragma unroll
        for (int r = 0; r < 2; ++r) {
            int oc = 16 + r;
            offs[((size_t)(g * 18 + oc)) * HWSZ + prow * 80 + pcol] = acc1[r] + b_off[oc];
        }
    }
}

// ---------------------------------------------------------------------------
// deformable conv: 2x16 px tile, K=1152 in 3 chunks of (3 taps x 128 ch).
// grid (5, 40, G), block 256 (4 waves x 32 o).  Plane/offs local g; out at n_base+g.
// ---------------------------------------------------------------------------
__global__ __launch_bounds__(256) void deform_gemm(const ushort* __restrict__ xTp,
                                                   const float* __restrict__ offs,
                                                   const ushort* __restrict__ wA,
                                                   const float* __restrict__ b,
                                                   float* __restrict__ out,
                                                   int n_base) {
    __shared__ ushort v_lds[32 * VSTR];  // 25088 B
    __shared__ int setup[288 * 8];       // 9216 B

    int t = threadIdx.x;
    int w0 = blockIdx.x * 16, h0 = blockIdx.y * 2, g = blockIdx.z;
    const ushort* xn = xTp + (size_t)g * PLANE;

    // ---- Phase 0: per-(tap,pixel) bilinear setup ----
    #pragma unroll
    for (int s = 0; s < 2; ++s) {
        int pair = t + s * 256;
        if (pair < 288) {
            int k = pair >> 5, p = pair & 31;
            int hh = h0 + (p >> 4), ww = w0 + (p & 15);
            size_t ob = ((size_t)(g * 18 + 2 * k)) * HWSZ + hh * 80 + ww;
            float dy = offs[ob], dx = offs[ob + HWSZ];
            int ky = k / 3, kx = k - ky * 3;
            float py = fminf(fmaxf((float)(hh + ky - 1) + dy, -7.5f), 86.5f);
            float px = fminf(fmaxf((float)(ww + kx - 1) + dx, -7.5f), 86.5f);
            float y0f = floorf(py), x0f = floorf(px);
            float fy = py - y0f, fx = px - x0f;
            int y0 = (int)y0f + 8, x0 = (int)x0f + 8;   // in [0,94]
            int rb0 = (y0 * PP + x0) * 128;
            setup[pair * 8 + 0] = rb0;
            setup[pair * 8 + 1] = rb0 + PP * 128;
            ((float*)setup)[pair * 8 + 2] = (1.f - fy) * (1.f - fx);
            ((float*)setup)[pair * 8 + 3] = (1.f - fy) * fx;
            ((float*)setup)[pair * 8 + 4] = fy * (1.f - fx);
            ((float*)setup)[pair * 8 + 5] = fy * fx;
        }
    }
    __syncthreads();

    int lane = t & 63;
    int o_t = (t >> 6) * 2;
    f32x4 acc[2][2];
    #pragma unroll
    for (int oi = 0; oi < 2; ++oi)
        #pragma unroll
        for (int pj = 0; pj < 2; ++pj) {
            f32x4 z = {0.f, 0.f, 0.f, 0.f};
            acc[oi][pj] = z;
        }

    for (int cc = 0; cc < 3; ++cc) {
        if (cc) __syncthreads();
        // ---- gather: 6 units/thread, 4 coalesced b128 corner loads each ----
        #pragma unroll
        for (int j = 0; j < 6; ++j) {
            int u = t + j * 256;
            int cg = u & 15;
            int pr = u >> 4;
            int tr = pr >> 5;
            int p  = pr & 31;
            int pair = (cc * 3 + tr) * 32 + p;
            const int* su = &setup[pair * 8];
            int rb0 = su[0], rb1 = su[1];
            float w00 = ((const float*)su)[2], w01 = ((const float*)su)[3];
            float w10 = ((const float*)su)[4], w11 = ((const float*)su)[5];
            const ushort* p0 = xn + rb0 + cg * 8;
            const ushort* p1 = xn + rb1 + cg * 8;
            bf16x8 g00 = *(const bf16x8*)p0;
            bf16x8 g01 = *(const bf16x8*)(p0 + 128);
            bf16x8 g10 = *(const bf16x8*)p1;
            bf16x8 g11 = *(const bf16x8*)(p1 + 128);
            uint r[4];
            #pragma unroll
            for (int c2 = 0; c2 < 4; ++c2) {
                float v0 = w00 * bf2f((ushort)g00[2 * c2])     + w01 * bf2f((ushort)g01[2 * c2])
                         + w10 * bf2f((ushort)g10[2 * c2])     + w11 * bf2f((ushort)g11[2 * c2]);
                float v1 = w00 * bf2f((ushort)g00[2 * c2 + 1]) + w01 * bf2f((ushort)g01[2 * c2 + 1])
                         + w10 * bf2f((ushort)g10[2 * c2 + 1]) + w11 * bf2f((ushort)g11[2 * c2 + 1]);
                r[c2] = pk2(v0, v1);
            }
            u32x4 rv = {r[0], r[1], r[2], r[3]};
            *(u32x4*)(v_lds + p * VSTR + tr * 128 + cg * 8) = rv;
        }
        __syncthreads();
        // ---- MFMA: 12 K-steps (3 taps x 128 ch) ----
        #pragma unroll
        for (int s = 0; s < 12; ++s) {
            int S = cc * 12 + s;
            bf16x8 a0 = *(const bf16x8*)(wA + ((size_t)(o_t * 36 + S) * 64 + lane) * 8);
            bf16x8 a1 = *(const bf16x8*)(wA + ((size_t)((o_t + 1) * 36 + S) * 64 + lane) * 8);
            const ushort* vb = v_lds + (lane & 15) * VSTR + s * 32 + 8 * (lane >> 4);
            bf16x8 b0 = *(const bf16x8*)vb;
            bf16x8 b1 = *(const bf16x8*)(vb + 16 * VSTR);
            acc[0][0] = __builtin_amdgcn_mfma_f32_16x16x32_bf16(a0, b0, acc[0][0], 0, 0, 0);
            acc[0][1] = __builtin_amdgcn_mfma_f32_16x16x32_bf16(a0, b1, acc[0][1], 0, 0, 0);
            acc[1][0] = __builtin_amdgcn_mfma_f32_16x16x32_bf16(a1, b0, acc[1][0], 0, 0, 0);
            acc[1][1] = __builtin_amdgcn_mfma_f32_16x16x32_bf16(a1, b1, acc[1][1], 0, 0, 0);
        }
    }

    // ---- epilogue: bias + store ----
    int o_w = (t >> 6) * 32;
    int n = n_base + g;
    #pragma unroll
    for (int oi = 0; oi < 2; ++oi)
        #pragma unroll
        for (int pj = 0; pj < 2; ++pj)
            #pragma unroll
            for (int r = 0; r < 4; ++r) {
                int o = o_w + oi * 16 + (lane >> 4) * 4 + r;
                int col = lane & 15;
                out[((size_t)(n * 128 + o)) * HWSZ + (h0 + pj) * 80 + w0 + col]
                    = acc[oi][pj][r] + b[o];
            }
}

// ---------------------------------------------------------------------------
extern "C" void kernel_launch(void* const* d_in, const int* in_sizes, int n_in,
                              void* d_out, int out_size, void* d_ws, size_t ws_size,
                              hipStream_t stream) {
    const float* x     = (const float*)d_in[0];   // (8,128,80,80)
    const float* w_off = (const float*)d_in[1];   // (18,128,3,3)
    const float* b_off = (const float*)d_in[2];   // (18,)
    const float* wmain = (const float*)d_in[3];   // (128,128,3,3)
    const float* bias  = (const float*)d_in[4];   // (128,)
    float* out = (float*)d_out;                   // (8,128,80,80)

    const size_t offsB_full = 8u * 18u * HWSZ * 4u;        // 3,686,400
    const size_t planeB     = (size_t)PLANE * 2u;          // 2,359,296
    const bool big = ws_size >= (offsB_full + 8 * planeB + 294912 + 73728);

    if (big) {
        // single-pass layout: offs | planes(8) | wA | wAoff  (22.93 MB)
        float*  offs  = (float*)d_ws;
        ushort* xTp   = (ushort*)((char*)d_ws + offsB_full);
        ushort* wA    = (ushort*)((char*)xTp + 8 * planeB);
        ushort* wAoff = (ushort*)((char*)wA + 294912);

        hipMemsetAsync(xTp, 0, 8 * planeB, stream);
        prep_weights<<<720, 256, 0, stream>>>(wmain, w_off, wA, wAoff);
        transpose_x<<<dim3(80, 8), 256, 0, stream>>>(x, xTp, 0);
        offset_mfma<<<dim3(5, 20, 8), 256, 0, stream>>>(xTp, wAoff, b_off, offs);
        deform_gemm<<<dim3(5, 40, 8), 256, 0, stream>>>(xTp, offs, wA, bias, out, 0);
    } else {
        // per-n layout: plane(1) | offs(1) | wA | wAoff  (3.19 MB, proven-safe)
        ushort* xTp   = (ushort*)d_ws;
        float*  offs  = (float*)((char*)d_ws + planeB);
        ushort* wA    = (ushort*)((char*)offs + 18u * HWSZ * 4u);
        ushort* wAoff = (ushort*)((char*)wA + 294912);

        hipMemsetAsync(xTp, 0, planeB, stream);   // borders stay zero across n
        prep_weights<<<720, 256, 0, stream>>>(wmain, w_off, wA, wAoff);
        for (int n = 0; n < 8; ++n) {
            transpose_x<<<dim3(80, 1), 256, 0, stream>>>(x, xTp, n);
            offset_mfma<<<dim3(5, 20, 1), 256, 0, stream>>>(xTp, wAoff, b_off, offs);
            deform_gemm<<<dim3(5, 40, 1), 256, 0, stream>>>(xTp, offs, wA, bias, out, n);
        }
    }
}

// Round 6
// 80.570 us; speedup vs baseline: 11.1680x; 1.0524x over previous
//
#include <hip/hip_runtime.h>

#define HWSZ 6400          // 80*80
#define PP   96            // padded plane dim (y,x in [-8,87])
#define PLANE (PP*PP*128)  // elems per padded plane (1,179,648; 2,359,296 B)

typedef short bf16x8 __attribute__((ext_vector_type(8)));
typedef float f32x4  __attribute__((ext_vector_type(4)));
typedef float f32x2  __attribute__((ext_vector_type(2)));
typedef uint  u32x4  __attribute__((ext_vector_type(4)));

__device__ inline ushort f2bf(float f) {
    uint u = __float_as_uint(f);
    u += 0x7fffu + ((u >> 16) & 1u);     // RNE
    return (ushort)(u >> 16);
}

// ---------------------------------------------------------------------------
// prep: fragment-major bf16 weights.
//   wA   [ot 0..7][S 0..35][lane 0..63][j 0..7]  (main conv, o = ot*16+(lane&15))
//   wAoff[ot 0..1][S 0..35][lane 0..63][j 0..7]  (offset conv, rows >=18 zero)
//   K = S*32 + 8*(lane>>4) + j ; tap k = K>>7 ; c = K&127  (tap-major K)
// ---------------------------------------------------------------------------
__global__ __launch_bounds__(256) void prep_weights(const float* __restrict__ w,
                                                    const float* __restrict__ w_off,
                                                    ushort* __restrict__ wA,
                                                    ushort* __restrict__ wAoff) {
    int idx = blockIdx.x * 256 + threadIdx.x;
    if (idx < 147456) {
        int ot = idx / 18432, rem = idx - ot * 18432;
        int s = rem >> 9, lane = (rem >> 3) & 63, j = rem & 7;
        int o = ot * 16 + (lane & 15);
        int K = s * 32 + 8 * (lane >> 4) + j;
        int k = K >> 7, c = K & 127;
        wA[idx] = f2bf(w[(o * 128 + c) * 9 + k]);
    } else if (idx < 147456 + 36864) {
        int i = idx - 147456;
        int ot = i / 18432, rem = i - ot * 18432;
        int s = rem >> 9, lane = (rem >> 3) & 63, j = rem & 7;
        int o = ot * 16 + (lane & 15);
        int K = s * 32 + 8 * (lane >> 4) + j;
        int k = K >> 7, c = K & 127;
        wAoff[i] = (o < 18) ? f2bf(w_off[(o * 128 + c) * 9 + k]) : (ushort)0;
    }
}

// ---------------------------------------------------------------------------
// transpose x -> padded NHWC bf16 plane g, WRITING the zero borders too
// (replaces the 18.9 MB memset).  grid (96 padded rows, G), block 256.
// ---------------------------------------------------------------------------
__global__ __launch_bounds__(256) void transpose_x(const float* __restrict__ x,
                                                   ushort* __restrict__ xTp,
                                                   int n_base) {
    __shared__ ushort st[80 * 136];      // [w][c]; 136 -> 16B-aligned rows
    int hp = blockIdx.x, g = blockIdx.y; // hp = padded row 0..95
    int t = threadIdx.x;
    const bool interior = (hp >= 8) && (hp < 88);
    if (interior) {
        int h = hp - 8;
        const float* xn = x + ((size_t)(n_base + g) * 128) * HWSZ + h * 80;
        for (int i = 0; i < 40; ++i) {
            int e = t + i * 256;         // e = c*80 + w   (10240 total)
            int c = e / 80;
            int wcol = e - c * 80;
            st[wcol * 136 + c] = f2bf(xn[(size_t)c * HWSZ + wcol]);
        }
        __syncthreads();
    }
    ushort* dst = xTp + (size_t)g * PLANE + (size_t)hp * PP * 128;
    for (int i = 0; i < 6; ++i) {
        int e = t + i * 256;             // 1536 x 16B units: col*16 + cq
        int col = e >> 4, cq = e & 15;
        u32x4 v = {0u, 0u, 0u, 0u};
        if (interior && col >= 8 && col < 88)
            v = *(const u32x4*)(st + (col - 8) * 136 + cq * 8);
        *(u32x4*)(dst + (size_t)col * 128 + cq * 8) = v;
    }
}

// ---------------------------------------------------------------------------
// offset conv as MFMA im2col GEMM.  Tile 4x16 px, 4 waves (one px-row each).
// grid (5, 20, G), block 256.  Plane g -> offs[g].
// ---------------------------------------------------------------------------
__global__ __launch_bounds__(256) void offset_mfma(const ushort* __restrict__ xTp,
                                                   const ushort* __restrict__ wAoff,
                                                   const float* __restrict__ b_off,
                                                   float* __restrict__ offs) {
    __shared__ ushort xs[6 * 18 * 136];  // 29376 B
    int t = threadIdx.x;
    int w0 = blockIdx.x * 16, h0 = blockIdx.y * 4, g = blockIdx.z;
    const ushort* xb = xTp + (size_t)g * PLANE + ((size_t)(h0 + 7) * PP + (w0 + 7)) * 128;
    for (int i = 0; i < 7; ++i) {
        int e = t + i * 256;
        if (e < 1728) {                  // 6 rows x 18 cols x 16 cq
            int r = e / 288, rem = e - r * 288;
            int col = rem >> 4, cq = rem & 15;
            u32x4 v = *(const u32x4*)(xb + ((size_t)r * PP + col) * 128 + cq * 8);
            *(u32x4*)(xs + (r * 18 + col) * 136 + cq * 8) = v;
        }
    }
    __syncthreads();
    int lane = t & 63, wv = t >> 6;
    f32x4 acc0 = {0.f, 0.f, 0.f, 0.f};
    f32x4 acc1 = {0.f, 0.f, 0.f, 0.f};
    #pragma unroll
    for (int k = 0; k < 9; ++k) {
        int ky = k / 3, kx = k - ky * 3;
        #pragma unroll
        for (int q = 0; q < 4; ++q) {
            int s = k * 4 + q;
            bf16x8 a0 = *(const bf16x8*)(wAoff + ((size_t)(0 * 36 + s) * 64 + lane) * 8);
            bf16x8 a1 = *(const bf16x8*)(wAoff + ((size_t)(1 * 36 + s) * 64 + lane) * 8);
            bf16x8 bb = *(const bf16x8*)(xs + ((wv + ky) * 18 + (lane & 15) + kx) * 136
                                          + q * 32 + 8 * (lane >> 4));
            acc0 = __builtin_amdgcn_mfma_f32_16x16x32_bf16(a0, bb, acc0, 0, 0, 0);
            acc1 = __builtin_amdgcn_mfma_f32_16x16x32_bf16(a1, bb, acc1, 0, 0, 0);
        }
    }
    int col = lane & 15, rg = lane >> 4;
    int prow = h0 + wv, pcol = w0 + col;
    #pragma unroll
    for (int r = 0; r < 4; ++r) {
        int oc = rg * 4 + r;
        offs[((size_t)(g * 18 + oc)) * HWSZ + prow * 80 + pcol] = acc0[r] + b_off[oc];
    }
    if (rg == 0) {
        #pragma unroll
        for (int r = 0; r < 2; ++r) {
            int oc = 16 + r;
            offs[((size_t)(g * 18 + oc)) * HWSZ + prow * 80 + pcol] = acc1[r] + b_off[oc];
        }
    }
}

// ---------------------------------------------------------------------------
// deformable conv: 2x16 px tile, K=1152 in 3 chunks of (3 taps x 128 ch).
//   v_lds rows (per pixel) 768 B, XOR-swizzled: byte ^= (p&7)<<4 on BOTH the
//   gather write and the MFMA fragment read (same involution, rule #21).
//   Gather math in packed f32 pairs + v_cvt_pk_bf16_f32.
// grid (5, 40, G), block 256 (4 waves x 32 o).
// ---------------------------------------------------------------------------
__global__ __launch_bounds__(256) void deform_gemm(const ushort* __restrict__ xTp,
                                                   const float* __restrict__ offs,
                                                   const ushort* __restrict__ wA,
                                                   const float* __restrict__ b,
                                                   float* __restrict__ out,
                                                   int n_base) {
    __shared__ ushort v_lds[32 * 384];   // 24576 B (swizzled)
    __shared__ int setup[288 * 8];       // 9216 B

    int t = threadIdx.x;
    int w0 = blockIdx.x * 16, h0 = blockIdx.y * 2, g = blockIdx.z;
    const ushort* xn = xTp + (size_t)g * PLANE;

    // ---- Phase 0: per-(tap,pixel) bilinear setup ----
    #pragma unroll
    for (int s = 0; s < 2; ++s) {
        int pair = t + s * 256;
        if (pair < 288) {
            int k = pair >> 5, p = pair & 31;
            int hh = h0 + (p >> 4), ww = w0 + (p & 15);
            size_t ob = ((size_t)(g * 18 + 2 * k)) * HWSZ + hh * 80 + ww;
            float dy = offs[ob], dx = offs[ob + HWSZ];
            int ky = k / 3, kx = k - ky * 3;
            float py = fminf(fmaxf((float)(hh + ky - 1) + dy, -7.5f), 86.5f);
            float px = fminf(fmaxf((float)(ww + kx - 1) + dx, -7.5f), 86.5f);
            float y0f = floorf(py), x0f = floorf(px);
            float fy = py - y0f, fx = px - x0f;
            int y0 = (int)y0f + 8, x0 = (int)x0f + 8;   // in [0,94]
            int rb0 = (y0 * PP + x0) * 128;
            setup[pair * 8 + 0] = rb0;
            setup[pair * 8 + 1] = rb0 + PP * 128;
            ((float*)setup)[pair * 8 + 2] = (1.f - fy) * (1.f - fx);
            ((float*)setup)[pair * 8 + 3] = (1.f - fy) * fx;
            ((float*)setup)[pair * 8 + 4] = fy * (1.f - fx);
            ((float*)setup)[pair * 8 + 5] = fy * fx;
        }
    }
    __syncthreads();

    int lane = t & 63;
    int o_t = (t >> 6) * 2;
    f32x4 acc[2][2];
    #pragma unroll
    for (int oi = 0; oi < 2; ++oi)
        #pragma unroll
        for (int pj = 0; pj < 2; ++pj) {
            f32x4 z = {0.f, 0.f, 0.f, 0.f};
            acc[oi][pj] = z;
        }

    const int m  = lane & 15;            // fragment row (pixel 0..15)
    const int q16 = (lane >> 4) * 16;    // k-subgroup byte offset
    const int xorc = (m & 7) << 4;       // read-side swizzle constant

    for (int cc = 0; cc < 3; ++cc) {
        if (cc) __syncthreads();
        // ---- gather: 6 units/thread; packed-f32 bilinear; swizzled write ----
        #pragma unroll
        for (int j = 0; j < 6; ++j) {
            int u = t + j * 256;
            int cg = u & 15;             // channel-group (8 ch)
            int pr = u >> 4;             // 0..95
            int tr = pr >> 5;            // tap within chunk
            int p  = pr & 31;            // pixel
            int pair = (cc * 3 + tr) * 32 + p;
            const int* su = &setup[pair * 8];
            int rb0 = su[0], rb1 = su[1];
            float w00 = ((const float*)su)[2], w01 = ((const float*)su)[3];
            float w10 = ((const float*)su)[4], w11 = ((const float*)su)[5];
            f32x2 W00 = {w00, w00}, W01 = {w01, w01};
            f32x2 W10 = {w10, w10}, W11 = {w11, w11};
            const ushort* p0 = xn + rb0 + cg * 8;
            const ushort* p1 = xn + rb1 + cg * 8;
            u32x4 g00 = *(const u32x4*)p0;
            u32x4 g01 = *(const u32x4*)(p0 + 128);
            u32x4 g10 = *(const u32x4*)p1;
            u32x4 g11 = *(const u32x4*)(p1 + 128);
            uint rr[4];
            #pragma unroll
            for (int c2 = 0; c2 < 4; ++c2) {
                f32x2 a00 = {__uint_as_float(g00[c2] << 16),
                             __uint_as_float(g00[c2] & 0xffff0000u)};
                f32x2 a01 = {__uint_as_float(g01[c2] << 16),
                             __uint_as_float(g01[c2] & 0xffff0000u)};
                f32x2 a10 = {__uint_as_float(g10[c2] << 16),
                             __uint_as_float(g10[c2] & 0xffff0000u)};
                f32x2 a11 = {__uint_as_float(g11[c2] << 16),
                             __uint_as_float(g11[c2] & 0xffff0000u)};
                f32x2 av = a00 * W00;
                av = __builtin_elementwise_fma(a01, W01, av);
                av = __builtin_elementwise_fma(a10, W10, av);
                av = __builtin_elementwise_fma(a11, W11, av);
                uint pk;
                asm("v_cvt_pk_bf16_f32 %0, %1, %2" : "=v"(pk) : "v"(av[0]), "v"(av[1]));
                rr[c2] = pk;
            }
            u32x4 rv = {rr[0], rr[1], rr[2], rr[3]};
            int wb = p * 768 + ((tr * 256 + cg * 16) ^ ((p & 7) << 4));
            *(u32x4*)((char*)v_lds + wb) = rv;
        }
        __syncthreads();
        // ---- MFMA: 12 K-steps (3 taps x 128 ch), swizzled b128 reads ----
        #pragma unroll
        for (int s = 0; s < 12; ++s) {
            int S = cc * 12 + s;
            bf16x8 a0 = *(const bf16x8*)(wA + ((size_t)(o_t * 36 + S) * 64 + lane) * 8);
            bf16x8 a1 = *(const bf16x8*)(wA + ((size_t)((o_t + 1) * 36 + S) * 64 + lane) * 8);
            int rb = m * 768 + ((s * 64 + q16) ^ xorc);
            bf16x8 b0 = *(const bf16x8*)((const char*)v_lds + rb);
            bf16x8 b1 = *(const bf16x8*)((const char*)v_lds + rb + 16 * 768);
            acc[0][0] = __builtin_amdgcn_mfma_f32_16x16x32_bf16(a0, b0, acc[0][0], 0, 0, 0);
            acc[0][1] = __builtin_amdgcn_mfma_f32_16x16x32_bf16(a0, b1, acc[0][1], 0, 0, 0);
            acc[1][0] = __builtin_amdgcn_mfma_f32_16x16x32_bf16(a1, b0, acc[1][0], 0, 0, 0);
            acc[1][1] = __builtin_amdgcn_mfma_f32_16x16x32_bf16(a1, b1, acc[1][1], 0, 0, 0);
        }
    }

    // ---- epilogue: bias + store ----
    int o_w = (t >> 6) * 32;
    int n = n_base + g;
    #pragma unroll
    for (int oi = 0; oi < 2; ++oi)
        #pragma unroll
        for (int pj = 0; pj < 2; ++pj)
            #pragma unroll
            for (int r = 0; r < 4; ++r) {
                int o = o_w + oi * 16 + (lane >> 4) * 4 + r;
                int col = lane & 15;
                out[((size_t)(n * 128 + o)) * HWSZ + (h0 + pj) * 80 + w0 + col]
                    = acc[oi][pj][r] + b[o];
            }
}

// ---------------------------------------------------------------------------
extern "C" void kernel_launch(void* const* d_in, const int* in_sizes, int n_in,
                              void* d_out, int out_size, void* d_ws, size_t ws_size,
                              hipStream_t stream) {
    const float* x     = (const float*)d_in[0];   // (8,128,80,80)
    const float* w_off = (const float*)d_in[1];   // (18,128,3,3)
    const float* b_off = (const float*)d_in[2];   // (18,)
    const float* wmain = (const float*)d_in[3];   // (128,128,3,3)
    const float* bias  = (const float*)d_in[4];   // (128,)
    float* out = (float*)d_out;                   // (8,128,80,80)

    const size_t offsB_full = 8u * 18u * HWSZ * 4u;        // 3,686,400
    const size_t planeB     = (size_t)PLANE * 2u;          // 2,359,296
    const bool big = ws_size >= (offsB_full + 8 * planeB + 294912 + 73728);

    if (big) {
        // single-pass layout: offs | planes(8) | wA | wAoff  (22.93 MB)
        float*  offs  = (float*)d_ws;
        ushort* xTp   = (ushort*)((char*)d_ws + offsB_full);
        ushort* wA    = (ushort*)((char*)xTp + 8 * planeB);
        ushort* wAoff = (ushort*)((char*)wA + 294912);

        prep_weights<<<720, 256, 0, stream>>>(wmain, w_off, wA, wAoff);
        transpose_x<<<dim3(96, 8), 256, 0, stream>>>(x, xTp, 0);
        offset_mfma<<<dim3(5, 20, 8), 256, 0, stream>>>(xTp, wAoff, b_off, offs);
        deform_gemm<<<dim3(5, 40, 8), 256, 0, stream>>>(xTp, offs, wA, bias, out, 0);
    } else {
        // per-n layout: plane(1) | offs(1) | wA | wAoff  (3.19 MB)
        ushort* xTp   = (ushort*)d_ws;
        float*  offs  = (float*)((char*)d_ws + planeB);
        ushort* wA    = (ushort*)((char*)offs + 18u * HWSZ * 4u);
        ushort* wAoff = (ushort*)((char*)wA + 294912);

        prep_weights<<<720, 256, 0, stream>>>(wmain, w_off, wA, wAoff);
        for (int n = 0; n < 8; ++n) {
            transpose_x<<<dim3(96, 1), 256, 0, stream>>>(x, xTp, n);
            offset_mfma<<<dim3(5, 20, 1), 256, 0, stream>>>(xTp, wAoff, b_off, offs);
            deform_gemm<<<dim3(5, 40, 1), 256, 0, stream>>>(xTp, offs, wA, bias, out, n);
        }
    }
}